// Round 9
// baseline (111.581 us; speedup 1.0000x reference)
//
#include <hip/hip_runtime.h>
#include <hip/hip_bf16.h>

#define GRID_D 128
#define NSITES (GRID_D * GRID_D)   // 16384
#define HID 64
#define BATCH 64

#define WPB 4                       // waves per block
#define BLOCKS 4096
#define BLOCKS_PER_BATCH (BLOCKS / BATCH)       // 64
#define WAVES_TOTAL (BLOCKS * WPB)              // 16384
#define WAVES_PER_BATCH (WAVES_TOTAL / BATCH)   // 256
#define TILES_PER_WAVE (NSITES / (WAVES_PER_BATCH * 16))  // 4

typedef short bf16x8 __attribute__((ext_vector_type(8)));
typedef float f32x4  __attribute__((ext_vector_type(4)));

__device__ __forceinline__ unsigned short f2bf(float f) {
    return __builtin_bit_cast(unsigned short, __float2bfloat16(f));
}

// Per 16-site tile: lane l serves site l%16; k-group (l>>4) covers k=(l>>4)*8..+7
// of each K=32 step. Hidden layer = 8 MFMAs (2 K-steps x 4 N-tiles of 16).
// Output is a full site-sum -> C consumed as sum(relu(C[:,n])*W_post[n]),
// no transpose, no LDS, no atomics (block partial -> d_ws, kernel2 reduces).
// R8 lesson: 1-deep gather pipeline = null (compiler already hoists loads);
// dropped. This round: TILES_PER_WAVE 8->4, 2x blocks for TLP/tail smoothing.
// NOTE: no min-waves launch bound, no tile-loop unroll -- R4 showed spill.
__global__ __launch_bounds__(256)
void gauge_mfma(const float* __restrict__ x,
                const float* __restrict__ H,
                const float* __restrict__ W_emb,
                const float* __restrict__ b_emb,
                const float* __restrict__ W_hid,
                const float* __restrict__ b_hid,
                const float* __restrict__ W_post,
                float* __restrict__ ws)
{
    const int tid   = threadIdx.x;
    const int lane  = tid & 63;
    const int widx  = tid >> 6;
    const int wgid  = blockIdx.x * WPB + widx;
    const int b     = wgid / WAVES_PER_BATCH;
    const int wslot = wgid % WAVES_PER_BATCH;

    const int ls = lane & 15;         // site-in-tile (A row) == n-in-tile (B/C col)
    const int kl = (lane >> 4) * 8;   // k-chunk base within a K=32 step

    const float h00 = H[0], h01 = H[1], h10 = H[2], h11 = H[3];

    // ---- loop-invariant B fragments: B[k][n] = W_hid[k*64+n], k=s*32+kl+i, n=t*16+ls
    bf16x8 bfrag[4][2];
    #pragma unroll
    for (int t = 0; t < 4; ++t) {
        #pragma unroll
        for (int s = 0; s < 2; ++s) {
            union { bf16x8 v; unsigned short us[8]; } r;
            #pragma unroll
            for (int i = 0; i < 8; ++i)
                r.us[i] = f2bf(W_hid[(s * 32 + kl + i) * HID + t * 16 + ls]);
            bfrag[t][s] = r.v;
        }
    }

    // per-lane bias / post-weight for each N-tile (col = t*16+ls)
    float bh[4], wp[4];
    #pragma unroll
    for (int t = 0; t < 4; ++t) {
        bh[t] = b_hid[t * 16 + ls];
        wp[t] = W_post[t * 16 + ls];
    }

    // hoist loop-invariant b_emb slices (k = s*32+kl+i)
    float be[2][8];
    #pragma unroll
    for (int s = 0; s < 2; ++s) {
        const float4 v0 = *(const float4*)(b_emb + s * 32 + kl);
        const float4 v1 = *(const float4*)(b_emb + s * 32 + kl + 4);
        be[s][0] = v0.x; be[s][1] = v0.y; be[s][2] = v0.z; be[s][3] = v0.w;
        be[s][4] = v1.x; be[s][5] = v1.y; be[s][6] = v1.z; be[s][7] = v1.w;
    }

    const float* __restrict__ xb = x + (size_t)b * NSITES * 2;
    const int wbase = wslot * (16 * TILES_PER_WAVE);
    float o = 0.0f;

    for (int tile = 0; tile < TILES_PER_WAVE; ++tile) {
        const int site = wbase + tile * 16 + ls;
        const int xc = site & (GRID_D - 1);
        const int yc = site >> 7;
        const int n0 = xc + (((yc + 1) & (GRID_D - 1)) << 7);
        const int n1 = xc + (((yc - 1) & (GRID_D - 1)) << 7);
        const int n2 = ((xc - 1) & (GRID_D - 1)) + (yc << 7);
        const int n3 = ((xc + 1) & (GRID_D - 1)) + (yc << 7);

        const float2 xi = *(const float2*)(xb + 2 * site);
        const float2 xu = *(const float2*)(xb + 2 * n0);
        const float2 xd = *(const float2*)(xb + 2 * n1);
        const float2 xl = *(const float2*)(xb + 2 * n2);
        const float2 xr = *(const float2*)(xb + 2 * n3);

        const float s0 = xi.x * fmaf(h00, xu.x, h01 * xu.y) + xi.y * fmaf(h10, xu.x, h11 * xu.y);
        const float s1 = xi.x * fmaf(h00, xd.x, h01 * xd.y) + xi.y * fmaf(h10, xd.x, h11 * xd.y);
        const float s2 = xi.x * fmaf(h00, xl.x, h01 * xl.y) + xi.y * fmaf(h10, xl.x, h11 * xl.y);
        const float s3 = xi.x * fmaf(h00, xr.x, h01 * xr.y) + xi.y * fmaf(h10, xr.x, h11 * xr.y);

        // ---- A fragments: h1[k] = relu(b_emb[k] + sum_m s_m * W_emb[m][k]), k = s*32+kl+i
        bf16x8 afrag[2];
        #pragma unroll
        for (int s = 0; s < 2; ++s) {
            const int kb = s * 32 + kl;
            float hv[8];
            #pragma unroll
            for (int i = 0; i < 8; ++i) hv[i] = be[s][i];
            #pragma unroll
            for (int m = 0; m < 4; ++m) {
                const float sm = (m == 0) ? s0 : (m == 1) ? s1 : (m == 2) ? s2 : s3;
                const float4 w0 = *(const float4*)(W_emb + m * HID + kb);
                const float4 w1 = *(const float4*)(W_emb + m * HID + kb + 4);
                hv[0] = fmaf(sm, w0.x, hv[0]); hv[1] = fmaf(sm, w0.y, hv[1]);
                hv[2] = fmaf(sm, w0.z, hv[2]); hv[3] = fmaf(sm, w0.w, hv[3]);
                hv[4] = fmaf(sm, w1.x, hv[4]); hv[5] = fmaf(sm, w1.y, hv[5]);
                hv[6] = fmaf(sm, w1.z, hv[6]); hv[7] = fmaf(sm, w1.w, hv[7]);
            }
            union { bf16x8 v; unsigned short us[8]; } r;
            #pragma unroll
            for (int i = 0; i < 8; ++i)
                r.us[i] = f2bf(fmaxf(hv[i], 0.0f));
            afrag[s] = r.v;
        }

        // ---- hidden layer via MFMA + fused relu/post epilogue
        #pragma unroll
        for (int t = 0; t < 4; ++t) {
            f32x4 acc = { bh[t], bh[t], bh[t], bh[t] };   // bias init
            acc = __builtin_amdgcn_mfma_f32_16x16x32_bf16(afrag[0], bfrag[t][0], acc, 0, 0, 0);
            acc = __builtin_amdgcn_mfma_f32_16x16x32_bf16(afrag[1], bfrag[t][1], acc, 0, 0, 0);
            #pragma unroll
            for (int r = 0; r < 4; ++r)
                o = fmaf(fmaxf(acc[r], 0.0f), wp[t], o);
        }
    }

    // wave reduce, block reduce, one plain store per block (no atomics)
    #pragma unroll
    for (int off = 32; off > 0; off >>= 1)
        o += __shfl_down(o, off, 64);

    __shared__ float part[WPB];
    if (lane == 0) part[widx] = o;
    __syncthreads();
    if (tid == 0)
        ws[blockIdx.x] = part[0] + part[1] + part[2] + part[3];
}

// 64 threads: out[b] = sum of this batch's block partials + N*b_post
__global__ __launch_bounds__(64)
void gauge_reduce(const float* __restrict__ ws,
                  const float* __restrict__ b_post,
                  float* __restrict__ out)
{
    const int b = threadIdx.x;
    float t = (float)NSITES * b_post[0];
    #pragma unroll
    for (int j = 0; j < BLOCKS_PER_BATCH; ++j)
        t += ws[b * BLOCKS_PER_BATCH + j];
    out[b] = t;
}

extern "C" void kernel_launch(void* const* d_in, const int* in_sizes, int n_in,
                              void* d_out, int out_size, void* d_ws, size_t ws_size,
                              hipStream_t stream)
{
    const float* x      = (const float*)d_in[0];
    const float* H      = (const float*)d_in[1];
    const float* W_emb  = (const float*)d_in[2];
    const float* b_emb  = (const float*)d_in[3];
    const float* W_hid  = (const float*)d_in[4];
    const float* b_hid  = (const float*)d_in[5];
    const float* W_post = (const float*)d_in[6];
    const float* b_post = (const float*)d_in[7];
    float* out = (float*)d_out;
    float* ws  = (float*)d_ws;   // 4096 floats of scratch

    gauge_mfma<<<dim3(BLOCKS), dim3(256), 0, stream>>>(
        x, H, W_emb, b_emb, W_hid, b_hid, W_post, ws);
    gauge_reduce<<<dim3(1), dim3(64), 0, stream>>>(ws, b_post, out);
}

// Round 11
// 97.053 us; speedup vs baseline: 1.1497x; 1.1497x over previous
//
#include <hip/hip_runtime.h>
#include <hip/hip_bf16.h>

#define GRID_D 128
#define NSITES (GRID_D * GRID_D)   // 16384
#define HID 64
#define BATCH 64

#define WPB 4                       // waves per block
#define BLOCKS 2048
#define BLOCKS_PER_BATCH (BLOCKS / BATCH)        // 32
#define WAVES_PER_BATCH (BLOCKS_PER_BATCH * WPB) // 128
#define TILES_PER_WAVE (NSITES / (WAVES_PER_BATCH * 16))  // 8

typedef short bf16x8 __attribute__((ext_vector_type(8)));
typedef float f32x4  __attribute__((ext_vector_type(4)));

__device__ __forceinline__ unsigned short f2bf(float f) {
    return __builtin_bit_cast(unsigned short, __float2bfloat16(f));
}

// packed RNE f32->bf16 pair: dst = {lo16: bf16(a), hi16: bf16(b)} (T12 recipe)
__device__ __forceinline__ unsigned cvt_pk_bf16(float a, float b) {
    unsigned r;
    asm("v_cvt_pk_bf16_f32 %0, %1, %2" : "=v"(r) : "v"(a), "v"(b));
    return r;
}

union frag_u { bf16x8 v; unsigned u[4]; unsigned short us[8]; };

// Both layers on MFMA. Embedding (K=5: 4 gauge dots + bias slot) computed
// SWAPPED: D[khid][site] = sum_kemb W_emb^T[khid][kemb]*s[site][kemb], so the
// C/D layout (col=lane&15=site, row=(lane>>4)*4+r=khid_local) leaves each lane
// holding h1 for its OWN site -- feeding the hidden MFMA's A-fragment with a
// k-permutation kappa(kg,i)= s*32+((i&4)<<2)+kg*4+(i&3) that is absorbed into
// the precomputed W_hid B-fragment gather (A/B only need a CONSISTENT k-map).
// Epilogue: o += relu(h2)*W_post[col] summed over all sites -> ws, kernel2
// reduces. R4 lesson: no min-waves bound, no tile unroll (spill).
__global__ __launch_bounds__(256)
void gauge_mfma(const float* __restrict__ x,
                const float* __restrict__ H,
                const float* __restrict__ W_emb,
                const float* __restrict__ b_emb,
                const float* __restrict__ W_hid,
                const float* __restrict__ b_hid,
                const float* __restrict__ W_post,
                float* __restrict__ ws)
{
    const int tid   = threadIdx.x;
    const int lane  = tid & 63;
    const int widx  = tid >> 6;
    const int wgid  = blockIdx.x * WPB + widx;
    const int b     = wgid / WAVES_PER_BATCH;
    const int wslot = wgid % WAVES_PER_BATCH;

    const int  ls  = lane & 15;    // site-in-tile (A row / C col)
    const int  kg  = lane >> 4;    // k-group
    const bool kg0 = (kg == 0);

    const float h00 = H[0], h01 = H[1], h10 = H[2], h11 = H[3];

    // ---- hidden-layer B fragments with permuted k-map kappa
    bf16x8 bfrag[4][2];
    #pragma unroll
    for (int t = 0; t < 4; ++t) {
        #pragma unroll
        for (int s = 0; s < 2; ++s) {
            frag_u r;
            #pragma unroll
            for (int i = 0; i < 8; ++i) {
                const int khid = s * 32 + ((i & 4) << 2) + (kg << 2) + (i & 3);
                r.us[i] = f2bf(W_hid[khid * HID + t * 16 + ls]);
            }
            bfrag[t][s] = r.v;
        }
    }

    // ---- embedding A fragments (MFMA m covers khid = m*16..m*16+15):
    // lane row = ls -> khid = m*16+ls; k-slots (kg=0 only): kemb 0..3 = W_emb,
    // slot 4 = b_emb (bias via B-slot of 1.0)
    bf16x8 afe[4];
    #pragma unroll
    for (int m = 0; m < 4; ++m) {
        const int col = m * 16 + ls;
        const float w0 = W_emb[0 * HID + col];
        const float w1 = W_emb[1 * HID + col];
        const float w2 = W_emb[2 * HID + col];
        const float w3 = W_emb[3 * HID + col];
        const float bb = b_emb[col];
        frag_u r;
        r.u[0] = kg0 ? cvt_pk_bf16(w0, w1) : 0u;
        r.u[1] = kg0 ? cvt_pk_bf16(w2, w3) : 0u;
        r.u[2] = kg0 ? (unsigned)f2bf(bb) : 0u;   // slot4 = bias, slot5 = 0
        r.u[3] = 0u;
        afe[m] = r.v;
    }

    // per-lane bias / post-weight per N-tile (col = t*16+ls)
    float bh[4], wp[4];
    #pragma unroll
    for (int t = 0; t < 4; ++t) {
        bh[t] = b_hid[t * 16 + ls];
        wp[t] = W_post[t * 16 + ls];
    }

    const float* __restrict__ xb = x + (size_t)b * NSITES * 2;
    const int wbase = wslot * (16 * TILES_PER_WAVE);
    const unsigned sd2 = kg0 ? 0x00003F80u : 0u;   // B slot4 = bf16(1.0)
    float o = 0.0f;

    for (int tile = 0; tile < TILES_PER_WAVE; ++tile) {
        const int site = wbase + tile * 16 + ls;
        const int xc = site & (GRID_D - 1);
        const int yc = site >> 7;
        const int n0 = xc + (((yc + 1) & (GRID_D - 1)) << 7);
        const int n1 = xc + (((yc - 1) & (GRID_D - 1)) << 7);
        const int n2 = ((xc - 1) & (GRID_D - 1)) + (yc << 7);
        const int n3 = ((xc + 1) & (GRID_D - 1)) + (yc << 7);

        const float2 xi = *(const float2*)(xb + 2 * site);
        const float2 xu = *(const float2*)(xb + 2 * n0);
        const float2 xd = *(const float2*)(xb + 2 * n1);
        const float2 xl = *(const float2*)(xb + 2 * n2);
        const float2 xr = *(const float2*)(xb + 2 * n3);

        const float s0 = xi.x * fmaf(h00, xu.x, h01 * xu.y) + xi.y * fmaf(h10, xu.x, h11 * xu.y);
        const float s1 = xi.x * fmaf(h00, xd.x, h01 * xd.y) + xi.y * fmaf(h10, xd.x, h11 * xd.y);
        const float s2 = xi.x * fmaf(h00, xl.x, h01 * xl.y) + xi.y * fmaf(h10, xl.x, h11 * xl.y);
        const float s3 = xi.x * fmaf(h00, xr.x, h01 * xr.y) + xi.y * fmaf(h10, xr.x, h11 * xr.y);

        // ---- embedding B fragment: s-values of this lane's site (kg=0 only)
        frag_u bs;
        const unsigned p01 = cvt_pk_bf16(s0, s1);
        const unsigned p23 = cvt_pk_bf16(s2, s3);
        bs.u[0] = kg0 ? p01 : 0u;
        bs.u[1] = kg0 ? p23 : 0u;
        bs.u[2] = sd2;
        bs.u[3] = 0u;

        // ---- embedding layer: 4 MFMAs -> h1 (pre-relu, bias included)
        f32x4 D0 = {0.f, 0.f, 0.f, 0.f};
        f32x4 D1 = {0.f, 0.f, 0.f, 0.f};
        f32x4 D2 = {0.f, 0.f, 0.f, 0.f};
        f32x4 D3 = {0.f, 0.f, 0.f, 0.f};
        D0 = __builtin_amdgcn_mfma_f32_16x16x32_bf16(afe[0], bs.v, D0, 0, 0, 0);
        D1 = __builtin_amdgcn_mfma_f32_16x16x32_bf16(afe[1], bs.v, D1, 0, 0, 0);
        D2 = __builtin_amdgcn_mfma_f32_16x16x32_bf16(afe[2], bs.v, D2, 0, 0, 0);
        D3 = __builtin_amdgcn_mfma_f32_16x16x32_bf16(afe[3], bs.v, D3, 0, 0, 0);

        // relu + pack hidden A fragments (k-map kappa matches bfrag)
        #pragma unroll
        for (int r = 0; r < 4; ++r) {
            D0[r] = fmaxf(D0[r], 0.0f);
            D1[r] = fmaxf(D1[r], 0.0f);
            D2[r] = fmaxf(D2[r], 0.0f);
            D3[r] = fmaxf(D3[r], 0.0f);
        }
        frag_u ah0, ah1;
        ah0.u[0] = cvt_pk_bf16(D0[0], D0[1]);
        ah0.u[1] = cvt_pk_bf16(D0[2], D0[3]);
        ah0.u[2] = cvt_pk_bf16(D1[0], D1[1]);
        ah0.u[3] = cvt_pk_bf16(D1[2], D1[3]);
        ah1.u[0] = cvt_pk_bf16(D2[0], D2[1]);
        ah1.u[1] = cvt_pk_bf16(D2[2], D2[3]);
        ah1.u[2] = cvt_pk_bf16(D3[0], D3[1]);
        ah1.u[3] = cvt_pk_bf16(D3[2], D3[3]);

        // ---- hidden layer: 8 MFMAs + fused relu/post epilogue
        #pragma unroll
        for (int t = 0; t < 4; ++t) {
            f32x4 acc = { bh[t], bh[t], bh[t], bh[t] };
            acc = __builtin_amdgcn_mfma_f32_16x16x32_bf16(ah0.v, bfrag[t][0], acc, 0, 0, 0);
            acc = __builtin_amdgcn_mfma_f32_16x16x32_bf16(ah1.v, bfrag[t][1], acc, 0, 0, 0);
            #pragma unroll
            for (int r = 0; r < 4; ++r)
                o = fmaf(fmaxf(acc[r], 0.0f), wp[t], o);
        }
    }

    // wave reduce, block reduce, one plain store per block (no atomics)
    #pragma unroll
    for (int off = 32; off > 0; off >>= 1)
        o += __shfl_down(o, off, 64);

    __shared__ float part[WPB];
    if (lane == 0) part[widx] = o;
    __syncthreads();
    if (tid == 0)
        ws[blockIdx.x] = part[0] + part[1] + part[2] + part[3];
}

// 64 threads: out[b] = sum of this batch's 32 block partials + N*b_post
__global__ __launch_bounds__(64)
void gauge_reduce(const float* __restrict__ ws,
                  const float* __restrict__ b_post,
                  float* __restrict__ out)
{
    const int b = threadIdx.x;
    float t = (float)NSITES * b_post[0];
    #pragma unroll
    for (int j = 0; j < BLOCKS_PER_BATCH; ++j)
        t += ws[b * BLOCKS_PER_BATCH + j];
    out[b] = t;
}

extern "C" void kernel_launch(void* const* d_in, const int* in_sizes, int n_in,
                              void* d_out, int out_size, void* d_ws, size_t ws_size,
                              hipStream_t stream)
{
    const float* x      = (const float*)d_in[0];
    const float* H      = (const float*)d_in[1];
    const float* W_emb  = (const float*)d_in[2];
    const float* b_emb  = (const float*)d_in[3];
    const float* W_hid  = (const float*)d_in[4];
    const float* b_hid  = (const float*)d_in[5];
    const float* W_post = (const float*)d_in[6];
    const float* b_post = (const float*)d_in[7];
    float* out = (float*)d_out;
    float* ws  = (float*)d_ws;   // 2048 floats of scratch

    gauge_mfma<<<dim3(BLOCKS), dim3(256), 0, stream>>>(
        x, H, W_emb, b_emb, W_hid, b_hid, W_post, ws);
    gauge_reduce<<<dim3(1), dim3(64), 0, stream>>>(ws, b_post, out);
}

// Round 13
// 96.881 us; speedup vs baseline: 1.1517x; 1.0018x over previous
//
#include <hip/hip_runtime.h>
#include <hip/hip_bf16.h>

#define GRID_D 128
#define NSITES (GRID_D * GRID_D)   // 16384
#define HID 64
#define BATCH 64

#define WPB 4                       // waves per block
#define BLOCKS 2048
#define BLOCKS_PER_BATCH (BLOCKS / BATCH)        // 32
#define WAVES_PER_BATCH (BLOCKS_PER_BATCH * WPB) // 128
#define SITES_PER_WAVE (NSITES / WAVES_PER_BATCH) // 128
#define ITERS (SITES_PER_WAVE / 64)               // 2

typedef short bf16x8 __attribute__((ext_vector_type(8)));
typedef float f32x4  __attribute__((ext_vector_type(4)));

__device__ __forceinline__ unsigned short f2bf(float f) {
    return __builtin_bit_cast(unsigned short, __float2bfloat16(f));
}

// packed RNE f32->bf16 pair: dst = {lo16: bf16(a), hi16: bf16(b)}
__device__ __forceinline__ unsigned cvt_pk_bf16(float a, float b) {
    unsigned r;
    asm("v_cvt_pk_bf16_f32 %0, %1, %2" : "=v"(r) : "v"(a), "v"(b));
    return r;
}

union frag_u { bf16x8 v; unsigned u[4]; unsigned short us[8]; };

// Both layers on MFMA (verified k-map from R11). New in R12:
//  * 64 distinct sites per iteration: lane = site for gather + s-dots (was
//    4x-duplicated across k-groups); 2 shuffles/group redistribute packed s
//    to the kg0 B-fragment lanes.
//  * bfrag setup via v_cvt_pk_bf16_f32 pairs (kappa makes i,i+1 consecutive
//    khid) -- kills ~300 VALU of scalar RNE per wave.
//  * o[4] accumulators break the serial epilogue chain.
// kappa(kg,i) = s*32 + ((i&4)<<2) + kg*4 + (i&3), baked into bfrag gather;
// emb-MFMA D layout: col=lane&15=site-in-group, row=(lane>>4)*4+r=khid_local.
// R4 lesson: no min-waves bound (spill). R8: explicit load pipeline = null.
__global__ __launch_bounds__(256)
void gauge_mfma(const float* __restrict__ x,
                const float* __restrict__ H,
                const float* __restrict__ W_emb,
                const float* __restrict__ b_emb,
                const float* __restrict__ W_hid,
                const float* __restrict__ b_hid,
                const float* __restrict__ W_post,
                float* __restrict__ ws)
{
    const int tid   = threadIdx.x;
    const int lane  = tid & 63;
    const int widx  = tid >> 6;
    const int wgid  = blockIdx.x * WPB + widx;
    const int b     = wgid / WAVES_PER_BATCH;
    const int wslot = wgid % WAVES_PER_BATCH;

    const int  ls  = lane & 15;    // col within 16-wide fragment
    const int  kg  = lane >> 4;    // k-group
    const bool kg0 = (kg == 0);

    const float h00 = H[0], h01 = H[1], h10 = H[2], h11 = H[3];

    // ---- hidden-layer B fragments, kappa k-map, packed conversion
    bf16x8 bfrag[4][2];
    #pragma unroll
    for (int t = 0; t < 4; ++t) {
        #pragma unroll
        for (int s = 0; s < 2; ++s) {
            frag_u r;
            #pragma unroll
            for (int j = 0; j < 4; ++j) {
                const int i    = 2 * j;
                const int khid = s * 32 + ((i & 4) << 2) + (kg << 2) + (i & 3);
                r.u[j] = cvt_pk_bf16(W_hid[khid * HID + t * 16 + ls],
                                     W_hid[(khid + 1) * HID + t * 16 + ls]);
            }
            bfrag[t][s] = r.v;
        }
    }

    // ---- embedding A fragments: row ls <-> khid = m*16+ls; k-slots (kg0):
    // kemb 0..3 = W_emb rows, slot 4 = b_emb (bias rides B-slot of 1.0)
    bf16x8 afe[4];
    #pragma unroll
    for (int m = 0; m < 4; ++m) {
        const int col = m * 16 + ls;
        frag_u r;
        r.u[0] = kg0 ? cvt_pk_bf16(W_emb[0 * HID + col], W_emb[1 * HID + col]) : 0u;
        r.u[1] = kg0 ? cvt_pk_bf16(W_emb[2 * HID + col], W_emb[3 * HID + col]) : 0u;
        r.u[2] = kg0 ? (unsigned)f2bf(b_emb[col]) : 0u;
        r.u[3] = 0u;
        afe[m] = r.v;
    }

    // per-lane bias / post-weight per N-tile (col = t*16+ls)
    float bh[4], wp[4];
    #pragma unroll
    for (int t = 0; t < 4; ++t) {
        bh[t] = b_hid[t * 16 + ls];
        wp[t] = W_post[t * 16 + ls];
    }

    const float* __restrict__ xb = x + (size_t)b * NSITES * 2;
    const int wbase = wslot * SITES_PER_WAVE;
    const unsigned sd2 = kg0 ? 0x00003F80u : 0u;   // B slot4 = bf16(1.0)
    float o0 = 0.f, o1 = 0.f, o2 = 0.f, o3 = 0.f;

    for (int it = 0; it < ITERS; ++it) {
        // ---- 64 distinct sites: lane = site-in-iteration
        const int site = wbase + it * 64 + lane;
        const int xc = site & (GRID_D - 1);
        const int yc = site >> 7;
        const int n0 = xc + (((yc + 1) & (GRID_D - 1)) << 7);
        const int n1 = xc + (((yc - 1) & (GRID_D - 1)) << 7);
        const int n2 = ((xc - 1) & (GRID_D - 1)) + (yc << 7);
        const int n3 = ((xc + 1) & (GRID_D - 1)) + (yc << 7);

        const float2 xi = *(const float2*)(xb + 2 * site);
        const float2 xu = *(const float2*)(xb + 2 * n0);
        const float2 xd = *(const float2*)(xb + 2 * n1);
        const float2 xl = *(const float2*)(xb + 2 * n2);
        const float2 xr = *(const float2*)(xb + 2 * n3);

        const float s0 = xi.x * fmaf(h00, xu.x, h01 * xu.y) + xi.y * fmaf(h10, xu.x, h11 * xu.y);
        const float s1 = xi.x * fmaf(h00, xd.x, h01 * xd.y) + xi.y * fmaf(h10, xd.x, h11 * xd.y);
        const float s2 = xi.x * fmaf(h00, xl.x, h01 * xl.y) + xi.y * fmaf(h10, xl.x, h11 * xl.y);
        const float s3 = xi.x * fmaf(h00, xr.x, h01 * xr.y) + xi.y * fmaf(h10, xr.x, h11 * xr.y);

        const unsigned p01 = cvt_pk_bf16(s0, s1);
        const unsigned p23 = cvt_pk_bf16(s2, s3);

        // ---- 4 site-groups of 16; shuffle s-packs to kg0 lanes' k-slots
        #pragma unroll
        for (int g = 0; g < 4; ++g) {
            const unsigned q0 = __shfl(p01, (g << 4) + ls, 64);
            const unsigned q1 = __shfl(p23, (g << 4) + ls, 64);
            frag_u bs;
            bs.u[0] = kg0 ? q0 : 0u;
            bs.u[1] = kg0 ? q1 : 0u;
            bs.u[2] = sd2;
            bs.u[3] = 0u;

            // embedding: 4 MFMAs -> h1 (bias included, pre-relu)
            f32x4 D0 = {0.f, 0.f, 0.f, 0.f};
            f32x4 D1 = {0.f, 0.f, 0.f, 0.f};
            f32x4 D2 = {0.f, 0.f, 0.f, 0.f};
            f32x4 D3 = {0.f, 0.f, 0.f, 0.f};
            D0 = __builtin_amdgcn_mfma_f32_16x16x32_bf16(afe[0], bs.v, D0, 0, 0, 0);
            D1 = __builtin_amdgcn_mfma_f32_16x16x32_bf16(afe[1], bs.v, D1, 0, 0, 0);
            D2 = __builtin_amdgcn_mfma_f32_16x16x32_bf16(afe[2], bs.v, D2, 0, 0, 0);
            D3 = __builtin_amdgcn_mfma_f32_16x16x32_bf16(afe[3], bs.v, D3, 0, 0, 0);

            #pragma unroll
            for (int r = 0; r < 4; ++r) {
                D0[r] = fmaxf(D0[r], 0.0f);
                D1[r] = fmaxf(D1[r], 0.0f);
                D2[r] = fmaxf(D2[r], 0.0f);
                D3[r] = fmaxf(D3[r], 0.0f);
            }
            frag_u ah0, ah1;
            ah0.u[0] = cvt_pk_bf16(D0[0], D0[1]);
            ah0.u[1] = cvt_pk_bf16(D0[2], D0[3]);
            ah0.u[2] = cvt_pk_bf16(D1[0], D1[1]);
            ah0.u[3] = cvt_pk_bf16(D1[2], D1[3]);
            ah1.u[0] = cvt_pk_bf16(D2[0], D2[1]);
            ah1.u[1] = cvt_pk_bf16(D2[2], D2[3]);
            ah1.u[2] = cvt_pk_bf16(D3[0], D3[1]);
            ah1.u[3] = cvt_pk_bf16(D3[2], D3[3]);

            // hidden layer: 8 MFMAs + fused relu/post epilogue
            {
                f32x4 acc = { bh[0], bh[0], bh[0], bh[0] };
                acc = __builtin_amdgcn_mfma_f32_16x16x32_bf16(ah0.v, bfrag[0][0], acc, 0, 0, 0);
                acc = __builtin_amdgcn_mfma_f32_16x16x32_bf16(ah1.v, bfrag[0][1], acc, 0, 0, 0);
                #pragma unroll
                for (int r = 0; r < 4; ++r) o0 = fmaf(fmaxf(acc[r], 0.0f), wp[0], o0);
            }
            {
                f32x4 acc = { bh[1], bh[1], bh[1], bh[1] };
                acc = __builtin_amdgcn_mfma_f32_16x16x32_bf16(ah0.v, bfrag[1][0], acc, 0, 0, 0);
                acc = __builtin_amdgcn_mfma_f32_16x16x32_bf16(ah1.v, bfrag[1][1], acc, 0, 0, 0);
                #pragma unroll
                for (int r = 0; r < 4; ++r) o1 = fmaf(fmaxf(acc[r], 0.0f), wp[1], o1);
            }
            {
                f32x4 acc = { bh[2], bh[2], bh[2], bh[2] };
                acc = __builtin_amdgcn_mfma_f32_16x16x32_bf16(ah0.v, bfrag[2][0], acc, 0, 0, 0);
                acc = __builtin_amdgcn_mfma_f32_16x16x32_bf16(ah1.v, bfrag[2][1], acc, 0, 0, 0);
                #pragma unroll
                for (int r = 0; r < 4; ++r) o2 = fmaf(fmaxf(acc[r], 0.0f), wp[2], o2);
            }
            {
                f32x4 acc = { bh[3], bh[3], bh[3], bh[3] };
                acc = __builtin_amdgcn_mfma_f32_16x16x32_bf16(ah0.v, bfrag[3][0], acc, 0, 0, 0);
                acc = __builtin_amdgcn_mfma_f32_16x16x32_bf16(ah1.v, bfrag[3][1], acc, 0, 0, 0);
                #pragma unroll
                for (int r = 0; r < 4; ++r) o3 = fmaf(fmaxf(acc[r], 0.0f), wp[3], o3);
            }
        }
    }

    float o = (o0 + o1) + (o2 + o3);

    // wave reduce, block reduce, one plain store per block (no atomics)
    #pragma unroll
    for (int off = 32; off > 0; off >>= 1)
        o += __shfl_down(o, off, 64);

    __shared__ float part[WPB];
    if (lane == 0) part[widx] = o;
    __syncthreads();
    if (tid == 0)
        ws[blockIdx.x] = part[0] + part[1] + part[2] + part[3];
}

// 64 threads: out[b] = sum of this batch's 32 block partials + N*b_post
__global__ __launch_bounds__(64)
void gauge_reduce(const float* __restrict__ ws,
                  const float* __restrict__ b_post,
                  float* __restrict__ out)
{
    const int b = threadIdx.x;
    float t = (float)NSITES * b_post[0];
    #pragma unroll
    for (int j = 0; j < BLOCKS_PER_BATCH; ++j)
        t += ws[b * BLOCKS_PER_BATCH + j];
    out[b] = t;
}

extern "C" void kernel_launch(void* const* d_in, const int* in_sizes, int n_in,
                              void* d_out, int out_size, void* d_ws, size_t ws_size,
                              hipStream_t stream)
{
    const float* x      = (const float*)d_in[0];
    const float* H      = (const float*)d_in[1];
    const float* W_emb  = (const float*)d_in[2];
    const float* b_emb  = (const float*)d_in[3];
    const float* W_hid  = (const float*)d_in[4];
    const float* b_hid  = (const float*)d_in[5];
    const float* W_post = (const float*)d_in[6];
    const float* b_post = (const float*)d_in[7];
    float* out = (float*)d_out;
    float* ws  = (float*)d_ws;   // 2048 floats of scratch

    gauge_mfma<<<dim3(BLOCKS), dim3(256), 0, stream>>>(
        x, H, W_emb, b_emb, W_hid, b_hid, W_post, ws);
    gauge_reduce<<<dim3(1), dim3(64), 0, stream>>>(ws, b_post, out);
}

// Round 14
// 92.892 us; speedup vs baseline: 1.2012x; 1.0430x over previous
//
#include <hip/hip_runtime.h>
#include <hip/hip_bf16.h>

#define GRID_D 128
#define NSITES (GRID_D * GRID_D)   // 16384
#define HID 64
#define BATCH 64

#define WPB 4                       // waves per block
#define BLOCKS 1024                 // full single-shot residency: 4096 waves
#define BLOCKS_PER_BATCH (BLOCKS / BATCH)        // 16
#define WAVES_PER_BATCH (BLOCKS_PER_BATCH * WPB) // 64
#define SITES_PER_WAVE (NSITES / WAVES_PER_BATCH) // 256
#define ITERS (SITES_PER_WAVE / 64)               // 4

typedef short bf16x8 __attribute__((ext_vector_type(8)));
typedef float f32x4  __attribute__((ext_vector_type(4)));

__device__ __forceinline__ unsigned short f2bf(float f) {
    return __builtin_bit_cast(unsigned short, __float2bfloat16(f));
}

// packed RNE f32->bf16 pair: dst = {lo16: bf16(a), hi16: bf16(b)}
__device__ __forceinline__ unsigned cvt_pk_bf16(float a, float b) {
    unsigned r;
    asm("v_cvt_pk_bf16_f32 %0, %1, %2" : "=v"(r) : "v"(a), "v"(b));
    return r;
}

union frag_u { bf16x8 v; unsigned u[4]; unsigned short us[8]; };

// Both layers on MFMA (k-map verified R11); 64 distinct sites/iter with
// shuffle redistribution (R13). R14: BLOCKS 2048->1024 so ALL 4096 waves are
// resident in one shot (4 waves/SIMD at ~116 VGPR) -- tests the
// dispatch-rounds/occupancy-ramp theory; per-wave setup amortized 2x more.
// kappa(kg,i) = s*32 + ((i&4)<<2) + kg*4 + (i&3), baked into bfrag gather;
// emb-MFMA D layout: col=lane&15=site-in-group, row=(lane>>4)*4+r=khid_local.
// R4: no min-waves bound (spill). R8: explicit load pipeline = null.
__global__ __launch_bounds__(256)
void gauge_mfma(const float* __restrict__ x,
                const float* __restrict__ H,
                const float* __restrict__ W_emb,
                const float* __restrict__ b_emb,
                const float* __restrict__ W_hid,
                const float* __restrict__ b_hid,
                const float* __restrict__ W_post,
                float* __restrict__ ws)
{
    const int tid   = threadIdx.x;
    const int lane  = tid & 63;
    const int widx  = tid >> 6;
    const int wgid  = blockIdx.x * WPB + widx;
    const int b     = wgid / WAVES_PER_BATCH;
    const int wslot = wgid % WAVES_PER_BATCH;

    const int  ls  = lane & 15;    // col within 16-wide fragment
    const int  kg  = lane >> 4;    // k-group
    const bool kg0 = (kg == 0);

    const float h00 = H[0], h01 = H[1], h10 = H[2], h11 = H[3];

    // ---- hidden-layer B fragments, kappa k-map, packed conversion
    bf16x8 bfrag[4][2];
    #pragma unroll
    for (int t = 0; t < 4; ++t) {
        #pragma unroll
        for (int s = 0; s < 2; ++s) {
            frag_u r;
            #pragma unroll
            for (int j = 0; j < 4; ++j) {
                const int i    = 2 * j;
                const int khid = s * 32 + ((i & 4) << 2) + (kg << 2) + (i & 3);
                r.u[j] = cvt_pk_bf16(W_hid[khid * HID + t * 16 + ls],
                                     W_hid[(khid + 1) * HID + t * 16 + ls]);
            }
            bfrag[t][s] = r.v;
        }
    }

    // ---- embedding A fragments: row ls <-> khid = m*16+ls; k-slots (kg0):
    // kemb 0..3 = W_emb rows, slot 4 = b_emb (bias rides B-slot of 1.0)
    bf16x8 afe[4];
    #pragma unroll
    for (int m = 0; m < 4; ++m) {
        const int col = m * 16 + ls;
        frag_u r;
        r.u[0] = kg0 ? cvt_pk_bf16(W_emb[0 * HID + col], W_emb[1 * HID + col]) : 0u;
        r.u[1] = kg0 ? cvt_pk_bf16(W_emb[2 * HID + col], W_emb[3 * HID + col]) : 0u;
        r.u[2] = kg0 ? (unsigned)f2bf(b_emb[col]) : 0u;
        r.u[3] = 0u;
        afe[m] = r.v;
    }

    // per-lane bias / post-weight per N-tile (col = t*16+ls)
    float bh[4], wp[4];
    #pragma unroll
    for (int t = 0; t < 4; ++t) {
        bh[t] = b_hid[t * 16 + ls];
        wp[t] = W_post[t * 16 + ls];
    }

    const float* __restrict__ xb = x + (size_t)b * NSITES * 2;
    const int wbase = wslot * SITES_PER_WAVE;
    const unsigned sd2 = kg0 ? 0x00003F80u : 0u;   // B slot4 = bf16(1.0)
    float o0 = 0.f, o1 = 0.f, o2 = 0.f, o3 = 0.f;

    for (int it = 0; it < ITERS; ++it) {
        // ---- 64 distinct sites: lane = site-in-iteration
        const int site = wbase + it * 64 + lane;
        const int xc = site & (GRID_D - 1);
        const int yc = site >> 7;
        const int n0 = xc + (((yc + 1) & (GRID_D - 1)) << 7);
        const int n1 = xc + (((yc - 1) & (GRID_D - 1)) << 7);
        const int n2 = ((xc - 1) & (GRID_D - 1)) + (yc << 7);
        const int n3 = ((xc + 1) & (GRID_D - 1)) + (yc << 7);

        const float2 xi = *(const float2*)(xb + 2 * site);
        const float2 xu = *(const float2*)(xb + 2 * n0);
        const float2 xd = *(const float2*)(xb + 2 * n1);
        const float2 xl = *(const float2*)(xb + 2 * n2);
        const float2 xr = *(const float2*)(xb + 2 * n3);

        const float s0 = xi.x * fmaf(h00, xu.x, h01 * xu.y) + xi.y * fmaf(h10, xu.x, h11 * xu.y);
        const float s1 = xi.x * fmaf(h00, xd.x, h01 * xd.y) + xi.y * fmaf(h10, xd.x, h11 * xd.y);
        const float s2 = xi.x * fmaf(h00, xl.x, h01 * xl.y) + xi.y * fmaf(h10, xl.x, h11 * xl.y);
        const float s3 = xi.x * fmaf(h00, xr.x, h01 * xr.y) + xi.y * fmaf(h10, xr.x, h11 * xr.y);

        const unsigned p01 = cvt_pk_bf16(s0, s1);
        const unsigned p23 = cvt_pk_bf16(s2, s3);

        // ---- 4 site-groups of 16; shuffle s-packs to kg0 lanes' k-slots
        #pragma unroll
        for (int g = 0; g < 4; ++g) {
            const unsigned q0 = __shfl(p01, (g << 4) + ls, 64);
            const unsigned q1 = __shfl(p23, (g << 4) + ls, 64);
            frag_u bs;
            bs.u[0] = kg0 ? q0 : 0u;
            bs.u[1] = kg0 ? q1 : 0u;
            bs.u[2] = sd2;
            bs.u[3] = 0u;

            // embedding: 4 MFMAs -> h1 (bias included, pre-relu)
            f32x4 D0 = {0.f, 0.f, 0.f, 0.f};
            f32x4 D1 = {0.f, 0.f, 0.f, 0.f};
            f32x4 D2 = {0.f, 0.f, 0.f, 0.f};
            f32x4 D3 = {0.f, 0.f, 0.f, 0.f};
            D0 = __builtin_amdgcn_mfma_f32_16x16x32_bf16(afe[0], bs.v, D0, 0, 0, 0);
            D1 = __builtin_amdgcn_mfma_f32_16x16x32_bf16(afe[1], bs.v, D1, 0, 0, 0);
            D2 = __builtin_amdgcn_mfma_f32_16x16x32_bf16(afe[2], bs.v, D2, 0, 0, 0);
            D3 = __builtin_amdgcn_mfma_f32_16x16x32_bf16(afe[3], bs.v, D3, 0, 0, 0);

            #pragma unroll
            for (int r = 0; r < 4; ++r) {
                D0[r] = fmaxf(D0[r], 0.0f);
                D1[r] = fmaxf(D1[r], 0.0f);
                D2[r] = fmaxf(D2[r], 0.0f);
                D3[r] = fmaxf(D3[r], 0.0f);
            }
            frag_u ah0, ah1;
            ah0.u[0] = cvt_pk_bf16(D0[0], D0[1]);
            ah0.u[1] = cvt_pk_bf16(D0[2], D0[3]);
            ah0.u[2] = cvt_pk_bf16(D1[0], D1[1]);
            ah0.u[3] = cvt_pk_bf16(D1[2], D1[3]);
            ah1.u[0] = cvt_pk_bf16(D2[0], D2[1]);
            ah1.u[1] = cvt_pk_bf16(D2[2], D2[3]);
            ah1.u[2] = cvt_pk_bf16(D3[0], D3[1]);
            ah1.u[3] = cvt_pk_bf16(D3[2], D3[3]);

            // hidden layer: 8 MFMAs + fused relu/post epilogue
            {
                f32x4 acc = { bh[0], bh[0], bh[0], bh[0] };
                acc = __builtin_amdgcn_mfma_f32_16x16x32_bf16(ah0.v, bfrag[0][0], acc, 0, 0, 0);
                acc = __builtin_amdgcn_mfma_f32_16x16x32_bf16(ah1.v, bfrag[0][1], acc, 0, 0, 0);
                #pragma unroll
                for (int r = 0; r < 4; ++r) o0 = fmaf(fmaxf(acc[r], 0.0f), wp[0], o0);
            }
            {
                f32x4 acc = { bh[1], bh[1], bh[1], bh[1] };
                acc = __builtin_amdgcn_mfma_f32_16x16x32_bf16(ah0.v, bfrag[1][0], acc, 0, 0, 0);
                acc = __builtin_amdgcn_mfma_f32_16x16x32_bf16(ah1.v, bfrag[1][1], acc, 0, 0, 0);
                #pragma unroll
                for (int r = 0; r < 4; ++r) o1 = fmaf(fmaxf(acc[r], 0.0f), wp[1], o1);
            }
            {
                f32x4 acc = { bh[2], bh[2], bh[2], bh[2] };
                acc = __builtin_amdgcn_mfma_f32_16x16x32_bf16(ah0.v, bfrag[2][0], acc, 0, 0, 0);
                acc = __builtin_amdgcn_mfma_f32_16x16x32_bf16(ah1.v, bfrag[2][1], acc, 0, 0, 0);
                #pragma unroll
                for (int r = 0; r < 4; ++r) o2 = fmaf(fmaxf(acc[r], 0.0f), wp[2], o2);
            }
            {
                f32x4 acc = { bh[3], bh[3], bh[3], bh[3] };
                acc = __builtin_amdgcn_mfma_f32_16x16x32_bf16(ah0.v, bfrag[3][0], acc, 0, 0, 0);
                acc = __builtin_amdgcn_mfma_f32_16x16x32_bf16(ah1.v, bfrag[3][1], acc, 0, 0, 0);
                #pragma unroll
                for (int r = 0; r < 4; ++r) o3 = fmaf(fmaxf(acc[r], 0.0f), wp[3], o3);
            }
        }
    }

    float o = (o0 + o1) + (o2 + o3);

    // wave reduce, block reduce, one plain store per block (no atomics)
    #pragma unroll
    for (int off = 32; off > 0; off >>= 1)
        o += __shfl_down(o, off, 64);

    __shared__ float part[WPB];
    if (lane == 0) part[widx] = o;
    __syncthreads();
    if (tid == 0)
        ws[blockIdx.x] = part[0] + part[1] + part[2] + part[3];
}

// 64 threads: out[b] = sum of this batch's 16 block partials + N*b_post
__global__ __launch_bounds__(64)
void gauge_reduce(const float* __restrict__ ws,
                  const float* __restrict__ b_post,
                  float* __restrict__ out)
{
    const int b = threadIdx.x;
    float t = (float)NSITES * b_post[0];
    #pragma unroll
    for (int j = 0; j < BLOCKS_PER_BATCH; ++j)
        t += ws[b * BLOCKS_PER_BATCH + j];
    out[b] = t;
}

extern "C" void kernel_launch(void* const* d_in, const int* in_sizes, int n_in,
                              void* d_out, int out_size, void* d_ws, size_t ws_size,
                              hipStream_t stream)
{
    const float* x      = (const float*)d_in[0];
    const float* H      = (const float*)d_in[1];
    const float* W_emb  = (const float*)d_in[2];
    const float* b_emb  = (const float*)d_in[3];
    const float* W_hid  = (const float*)d_in[4];
    const float* b_hid  = (const float*)d_in[5];
    const float* W_post = (const float*)d_in[6];
    const float* b_post = (const float*)d_in[7];
    float* out = (float*)d_out;
    float* ws  = (float*)d_ws;   // 1024 floats of scratch

    gauge_mfma<<<dim3(BLOCKS), dim3(256), 0, stream>>>(
        x, H, W_emb, b_emb, W_hid, b_hid, W_post, ws);
    gauge_reduce<<<dim3(1), dim3(64), 0, stream>>>(ws, b_post, out);
}